// Round 10
// baseline (79.655 us; speedup 1.0000x reference)
//
#include <hip/hip_runtime.h>
#include <stdint.h>

// RadialAEVComputer: out[b,i,s*16+p] = sum_{j: 0<d<RC, spc(j)=s} exp(-16(d-shf_p)^2)*fc(d)
// B=64, N=256, S=4, P=16, RC=5.2, shf_p = 0.9 + 0.26875*p
// d_in[0]: fp32 [B,256,256]; d_in[1]: int32 [B,256] (1..4); d_out: fp32 [B,256,64]
//
// Block = 256 = 4 waves, TWO rows per wave (8 rows/block). Grid = B*32 = 2048
// = exactly 8 blocks/CU x 256 CU -> one resident generation, all global loads
// issued at entry (max MLP against the harness's L3-drain background).
// Phase A: per-b species permutation with segments PADDED to multiples of 8
//          (padding slots carry weight 0) -> phase C uses ds_read_b128 (2
//          pairs/instr), wave-uniform segment loops, zero selects.
// Phase C: lane=(p,q): quad-strided b128 over each species segment, 2 rows
//          interleaved (4 indep exp chains); quad shfl-reduce; 256B nt stores.

static __device__ __forceinline__ int mbcnt64(uint64_t m) {
    // popcount(m & lanemask_lt)
    int lo = __builtin_amdgcn_mbcnt_lo((uint32_t)m, 0u);
    return __builtin_amdgcn_mbcnt_hi((uint32_t)(m >> 32), lo);
}

__global__ __launch_bounds__(256) void aev_kernel(
    const float* __restrict__ dmat,      // fp32 [B,256,256]
    const int* __restrict__ species,     // int32 [B,256], values 1..4
    float* __restrict__ out)             // fp32 [B,256,64]
{
    __shared__ alignas(16) float2 comp[8][288]; // per-row permuted (d, fc*mask), 8-padded segments
    __shared__ alignas(16) int pos[256];        // species-major padded permutation of j
    __shared__ int cntm[4][4];                  // per-wave per-species counts

    const int tid  = threadIdx.x;
    const int w    = tid >> 6;
    const int lane = tid & 63;
    const int blk  = (int)blockIdx.x;
    const int row0 = blk * 8 + w * 2;    // global rows row0, row0+1
    const int b    = blk >> 5;           // 32 blocks per batch element

    // ---- issue both global row loads immediately ----
    const float4 qa = ((const float4*)(dmat + ((size_t)row0 << 8)))[lane];
    const float4 qb = ((const float4*)(dmat + ((size_t)(row0 + 1) << 8)))[lane];

    // ---- phase A: species ballots (permutation is per-b, rows share it) ----
    int sj = species[(b << 8) + tid] - 1;           // 0..3
    sj = (sj < 0) ? 0 : ((sj > 3) ? 3 : sj);        // insurance
    const uint64_t bs0 = __ballot((sj & 1) != 0);
    const uint64_t bs1 = __ballot((sj & 2) != 0);
    const uint64_t m0 = ~bs0 & ~bs1, m1 = bs0 & ~bs1;
    const uint64_t m2 = ~bs0 &  bs1, m3 = bs0 &  bs1;
    if (lane == 0) {
        cntm[w][0] = __popcll(m0); cntm[w][1] = __popcll(m1);
        cntm[w][2] = __popcll(m2); cntm[w][3] = __popcll(m3);
    }
    uint64_t msel = m0;
    msel = (sj == 1) ? m1 : msel;
    msel = (sj == 2) ? m2 : msel;
    msel = (sj == 3) ? m3 : msel;
    const int rank = mbcnt64(msel);

    // default-fill comp: padding slots read (2.6, 0) -> contribute exactly 0
    {
        float2* cz = &comp[0][0];                   // 8*288 = 2304 = 256*9
        #pragma unroll
        for (int k = 0; k < 9; ++k) cz[tid + 256 * k] = make_float2(2.6f, 0.0f);
    }
    __syncthreads();

    // ---- padded segment bases (uniform) + this thread's permuted slot ----
    int segP[5], nIt[4];
    segP[0] = 0;
    #pragma unroll
    for (int s = 0; s < 4; ++s) {
        const int t4  = cntm[0][s] + cntm[1][s] + cntm[2][s] + cntm[3][s];
        const int t4p = (t4 + 7) & ~7;              // round up to 8
        nIt[s]     = t4p >> 3;
        segP[s + 1] = segP[s] + t4p;                // <= 284 < 288
    }
    {
        int base = segP[0];
        base = (sj == 1) ? segP[1] : base;
        base = (sj == 2) ? segP[2] : base;
        base = (sj == 3) ? segP[3] : base;
        int wadd = 0;
        #pragma unroll
        for (int w2 = 0; w2 < 3; ++w2) wadd += (w2 < w) ? cntm[w2][sj] : 0;
        const int slot = base + wadd + rank;
        pos[tid] = (slot < 287) ? slot : 287;       // insurance
    }
    __syncthreads();

    // ---- phase B: scatter both rows into permuted LDS ----
    {
        const int4 p4 = *(const int4*)&pos[4 * lane];
        const int   pp[4] = {p4.x, p4.y, p4.z, p4.w};
        const float da[4] = {qa.x, qa.y, qa.z, qa.w};
        const float db[4] = {qb.x, qb.y, qb.z, qb.w};
        const int lr = w * 2;
        #pragma unroll
        for (int e = 0; e < 4; ++e) {
            const float dd = da[e];
            const bool  v  = (dd < 5.2f) && (dd != 0.0f);   // false for NaN
            const float x  = v ? dd : 2.6f;                 // cos arg in-domain
            const float fc = 0.5f * __builtin_amdgcn_cosf(x * (0.5f / 5.2f)) + 0.5f;
            comp[lr][pp[e]] = make_float2(x, v ? fc : 0.0f);
        }
        #pragma unroll
        for (int e = 0; e < 4; ++e) {
            const float dd = db[e];
            const bool  v  = (dd < 5.2f) && (dd != 0.0f);
            const float x  = v ? dd : 2.6f;
            const float fc = 0.5f * __builtin_amdgcn_cosf(x * (0.5f / 5.2f)) + 0.5f;
            comp[lr + 1][pp[e]] = make_float2(x, v ? fc : 0.0f);
        }
    }
    __syncthreads();

    // ---- phase C: lane = (p = shift, q = quad slot), b128 pair reads ----
    const int p = lane >> 2;             // 0..15
    const int q = lane & 3;              // 0..3
    const float shfp = 0.9f + 0.26875f * (float)p;
    const int lr = w * 2;
    float acc[2][4];
    #pragma unroll
    for (int s = 0; s < 4; ++s) {
        float a0 = 0.0f, a1 = 0.0f;
        const int k0 = segP[s] + 2 * q;
        const int n  = nIt[s];
        for (int m = 0; m < n; ++m) {
            const int k = k0 + 8 * m;    // even -> 16B-aligned
            const float4 f0 = *(const float4*)&comp[lr][k];      // (d0,w0,d1,w1)
            const float4 f1 = *(const float4*)&comp[lr + 1][k];
            float u;
            // exp(-16*u^2) = exp2(u^2 * -16*log2(e)); args <= 0, all finite
            u = f0.x - shfp; a0 = __builtin_fmaf(__builtin_amdgcn_exp2f(u * u * -23.083120654223414f), f0.y, a0);
            u = f0.z - shfp; a0 = __builtin_fmaf(__builtin_amdgcn_exp2f(u * u * -23.083120654223414f), f0.w, a0);
            u = f1.x - shfp; a1 = __builtin_fmaf(__builtin_amdgcn_exp2f(u * u * -23.083120654223414f), f1.y, a1);
            u = f1.z - shfp; a1 = __builtin_fmaf(__builtin_amdgcn_exp2f(u * u * -23.083120654223414f), f1.w, a1);
        }
        acc[0][s] = a0; acc[1][s] = a1;
    }
    // quad reduce (lanes 4p..4p+3 share p)
    #pragma unroll
    for (int rr = 0; rr < 2; ++rr)
        #pragma unroll
        for (int s = 0; s < 4; ++s) {
            acc[rr][s] += __shfl_xor(acc[rr][s], 1, 64);
            acc[rr][s] += __shfl_xor(acc[rr][s], 2, 64);
        }
    // lane (p,q) stores species s=q for both rows -> two coalesced 256B stores
    #pragma unroll
    for (int rr = 0; rr < 2; ++rr) {
        float vout = acc[rr][0];
        vout = (q == 1) ? acc[rr][1] : vout;
        vout = (q == 2) ? acc[rr][2] : vout;
        vout = (q == 3) ? acc[rr][3] : vout;
        __builtin_nontemporal_store(vout,
            &out[((size_t)(row0 + rr) << 6) + (size_t)((q << 4) + p)]);
    }
}

extern "C" void kernel_launch(void* const* d_in, const int* in_sizes, int n_in,
                              void* d_out, int out_size, void* d_ws, size_t ws_size,
                              hipStream_t stream) {
    const float* dmat  = (const float*)d_in[0];          // fp32 [B,256,256]
    const int* species = (const int*)d_in[1];            // int32 [B,256]
    float* o           = (float*)d_out;                  // fp32 [B,256,64]
    const int B = in_sizes[1] >> 8;                      // N = 256
    aev_kernel<<<dim3(B * 32), 256, 0, stream>>>(dmat, species, o);
}

// Round 12
// 75.834 us; speedup vs baseline: 1.0504x; 1.0504x over previous
//
#include <hip/hip_runtime.h>
#include <stdint.h>

// RadialAEVComputer: out[b,i,s*16+p] = sum_{j: 0<d<RC, spc(j)=s} exp(-16(d-shf_p)^2)*fc(d)
// B=64, N=256, S=4, P=16, RC=5.2, shf_p = 0.9 + 0.26875*p
// d_in[0]: fp32 [B,256,256]; d_in[1]: int32 [B,256] (1..4); d_out: fp32 [B,256,64]
//
// Block = 256 = 4 waves, 2 rows/wave (8 rows/block), grid = B*32 = 2048
// (one resident generation: 8 blocks/CU x 256 CU).
// Phase A: per-b species permutation (exact bijection, 2 ballots).
// Phase B: stage per pair (cA = K*d^2 + log2(fc*mask), cB = -2K*d); invalid
//          pairs get cA=-inf, cB=0 -> exp2 term is exactly 0, select-free.
// Phase C: lane = (g, q', s'): 4 shifts p=4g..4g+3, quad q' over the s'
//          segment; term = exp2(fma(cB, shf, cA) + K*shf^2). 8 exps per LDS
//          pair read (4p x 2rows). 2-step quad shfl reduce, LDS gather,
//          coalesced nontemporal 8B stores (native ext_vector, not HIP float2).

static __device__ __forceinline__ int mbcnt64(uint64_t m) {
    int lo = __builtin_amdgcn_mbcnt_lo((uint32_t)m, 0u);
    return __builtin_amdgcn_mbcnt_hi((uint32_t)(m >> 32), lo);
}

typedef float vfloat2 __attribute__((ext_vector_type(2)));

#define KNEG (-23.083120654223414f)   /* -16*log2(e) */

__global__ __launch_bounds__(256) void aev_kernel(
    const float* __restrict__ dmat,      // fp32 [B,256,256]
    const int* __restrict__ species,     // int32 [B,256], values 1..4
    float* __restrict__ out)             // fp32 [B,256,64]
{
    __shared__ alignas(16) float2 comp[8][256]; // per-row permuted (cA, cB)
    __shared__ alignas(16) int    pos[256];     // species-major permutation of j
    __shared__ alignas(16) float  red[8][64];   // per-row [s*16+p] results
    __shared__ int cntm[4][4];                  // per-wave per-species counts

    const int tid  = threadIdx.x;
    const int w    = tid >> 6;
    const int lane = tid & 63;
    const int blk  = (int)blockIdx.x;
    const int row0 = blk * 8 + w * 2;    // this wave's rows: row0, row0+1
    const int b    = blk >> 5;

    // ---- issue both global row loads immediately ----
    const float4 qa = ((const float4*)(dmat + ((size_t)row0 << 8)))[lane];
    const float4 qb = ((const float4*)(dmat + ((size_t)(row0 + 1) << 8)))[lane];

    // ---- phase A: per-b species permutation ----
    int sj = species[(b << 8) + tid] - 1;           // 0..3
    sj = (sj < 0) ? 0 : ((sj > 3) ? 3 : sj);        // insurance
    const uint64_t bs0 = __ballot((sj & 1) != 0);
    const uint64_t bs1 = __ballot((sj & 2) != 0);
    const uint64_t m0 = ~bs0 & ~bs1, m1 = bs0 & ~bs1;
    const uint64_t m2 = ~bs0 &  bs1, m3 = bs0 &  bs1;
    if (lane == 0) {
        cntm[w][0] = __popcll(m0); cntm[w][1] = __popcll(m1);
        cntm[w][2] = __popcll(m2); cntm[w][3] = __popcll(m3);
    }
    uint64_t msel = m0;
    msel = (sj == 1) ? m1 : msel;
    msel = (sj == 2) ? m2 : msel;
    msel = (sj == 3) ? m3 : msel;
    const int rank = mbcnt64(msel);
    __syncthreads();

    int seg[5];
    seg[0] = 0;
    #pragma unroll
    for (int s = 0; s < 4; ++s)
        seg[s + 1] = seg[s] + cntm[0][s] + cntm[1][s] + cntm[2][s] + cntm[3][s];
    {
        int base = seg[0];
        base = (sj == 1) ? seg[1] : base;
        base = (sj == 2) ? seg[2] : base;
        base = (sj == 3) ? seg[3] : base;
        int wadd = 0;
        #pragma unroll
        for (int w2 = 0; w2 < 3; ++w2) wadd += (w2 < w) ? cntm[w2][sj] : 0;
        pos[tid] = base + wadd + rank;              // exact bijection [0,256)
    }
    __syncthreads();

    // ---- phase B: stage both rows as (cA, cB), permuted ----
    {
        const int4 p4 = *(const int4*)&pos[4 * lane];
        const int   pp[4] = {p4.x, p4.y, p4.z, p4.w};
        const float da[4] = {qa.x, qa.y, qa.z, qa.w};
        const float db[4] = {qb.x, qb.y, qb.z, qb.w};
        const float NINF = -__builtin_inff();
        const int lr = w * 2;
        #pragma unroll
        for (int e = 0; e < 4; ++e) {
            const float dd = da[e];
            const bool  v  = (dd < 5.2f) && (dd != 0.0f);   // false for NaN
            const float x  = v ? dd : 2.6f;                 // cos arg in-domain
            const float fc = 0.5f * __builtin_amdgcn_cosf(x * (0.5f / 5.2f)) + 0.5f;
            const float cA = __builtin_fmaf(KNEG * x, x, __builtin_amdgcn_logf(fc));
            comp[lr][pp[e]] = make_float2(v ? cA : NINF, v ? (-2.0f * KNEG) * x : 0.0f);
        }
        #pragma unroll
        for (int e = 0; e < 4; ++e) {
            const float dd = db[e];
            const bool  v  = (dd < 5.2f) && (dd != 0.0f);
            const float x  = v ? dd : 2.6f;
            const float fc = 0.5f * __builtin_amdgcn_cosf(x * (0.5f / 5.2f)) + 0.5f;
            const float cA = __builtin_fmaf(KNEG * x, x, __builtin_amdgcn_logf(fc));
            comp[lr + 1][pp[e]] = make_float2(v ? cA : NINF, v ? (-2.0f * KNEG) * x : 0.0f);
        }
    }
    __syncthreads();

    // ---- phase C: lane = g*16 + q'*4 + s' ----
    const int g  = lane >> 4;            // 0..3 -> shifts p = 4g..4g+3
    const int qp = (lane >> 2) & 3;      // quad slot within segment
    const int sp = lane & 3;             // owned species segment
    const int lr = w * 2;

    float shf[4], kp[4];
    #pragma unroll
    for (int t = 0; t < 4; ++t) {
        shf[t] = 0.9f + 0.26875f * (float)(4 * g + t);
        kp[t]  = KNEG * shf[t] * shf[t];
    }

    const int sbeg = (sp == 0) ? seg[0] : (sp == 1) ? seg[1] : (sp == 2) ? seg[2] : seg[3];
    const int send = (sp == 0) ? seg[1] : (sp == 1) ? seg[2] : (sp == 2) ? seg[3] : seg[4];
    int maxLen = seg[1] - seg[0];
    maxLen = (seg[2] - seg[1] > maxLen) ? seg[2] - seg[1] : maxLen;
    maxLen = (seg[3] - seg[2] > maxLen) ? seg[3] - seg[2] : maxLen;
    maxLen = (seg[4] - seg[3] > maxLen) ? seg[4] - seg[3] : maxLen;
    const int nIt = (maxLen + 3) >> 2;   // wave-uniform trip count

    const float NINF = -__builtin_inff();
    float a0x = 0.f, a0y = 0.f, a0z = 0.f, a0w = 0.f;   // row0, t=0..3
    float a1x = 0.f, a1y = 0.f, a1z = 0.f, a1w = 0.f;   // row1
    for (int m = 0; m < nIt; ++m) {
        const int k  = sbeg + qp + 4 * m;
        const int kc = (k < 255) ? k : 255;
        const bool live = (k < send);
        const float2 cR0 = comp[lr][kc];
        const float2 cR1 = comp[lr + 1][kc];
        const float A0 = live ? cR0.x : NINF;
        const float A1 = live ? cR1.x : NINF;
        // term = exp2(cB*shf + cA + K*shf^2); dead lanes/tails -> exp2(-inf)=0
        #pragma unroll
        for (int t = 0; t < 4; ++t) {
            const float e0 = __builtin_amdgcn_exp2f(__builtin_fmaf(cR0.y, shf[t], A0) + kp[t]);
            const float e1 = __builtin_amdgcn_exp2f(__builtin_fmaf(cR1.y, shf[t], A1) + kp[t]);
            if (t == 0) { a0x += e0; a1x += e1; }
            if (t == 1) { a0y += e0; a1y += e1; }
            if (t == 2) { a0z += e0; a1z += e1; }
            if (t == 3) { a0w += e0; a1w += e1; }
        }
    }

    // ---- reduce over q' (lanes xor 4, 8) ----
    #pragma unroll
    for (int d = 4; d <= 8; d <<= 1) {
        a0x += __shfl_xor(a0x, d, 64); a0y += __shfl_xor(a0y, d, 64);
        a0z += __shfl_xor(a0z, d, 64); a0w += __shfl_xor(a0w, d, 64);
        a1x += __shfl_xor(a1x, d, 64); a1y += __shfl_xor(a1y, d, 64);
        a1z += __shfl_xor(a1z, d, 64); a1w += __shfl_xor(a1w, d, 64);
    }

    // lanes with q'==0 hold the (g, s') sums: write [s'*16 + 4g .. +3]
    if (qp == 0) {
        float4* r0 = (float4*)&red[lr][(sp << 4) + (g << 2)];
        float4* r1 = (float4*)&red[lr + 1][(sp << 4) + (g << 2)];
        *r0 = make_float4(a0x, a0y, a0z, a0w);
        *r1 = make_float4(a1x, a1y, a1z, a1w);
    }

    // ---- store: wave reads its own rows from red (wave-synchronous) ----
    {
        const int r  = lane >> 5;                   // 0..1 (this wave's rows)
        const int c2 = lane & 31;                   // float2 column
        const float2 rv = ((const float2*)&red[lr + r][0])[c2];
        vfloat2 nv; nv.x = rv.x; nv.y = rv.y;       // native vector for the builtin
        vfloat2* dst = (vfloat2*)&out[((size_t)(row0 + r) << 6) + (size_t)(c2 * 2)];
        __builtin_nontemporal_store(nv, dst);
    }
}

extern "C" void kernel_launch(void* const* d_in, const int* in_sizes, int n_in,
                              void* d_out, int out_size, void* d_ws, size_t ws_size,
                              hipStream_t stream) {
    const float* dmat  = (const float*)d_in[0];          // fp32 [B,256,256]
    const int* species = (const int*)d_in[1];            // int32 [B,256]
    float* o           = (float*)d_out;                  // fp32 [B,256,64]
    const int B = in_sizes[1] >> 8;                      // N = 256
    aev_kernel<<<dim3(B * 32), 256, 0, stream>>>(dmat, species, o);
}

// Round 13
// 75.712 us; speedup vs baseline: 1.0521x; 1.0016x over previous
//
#include <hip/hip_runtime.h>
#include <stdint.h>

// RadialAEVComputer: out[b,i,s*16+p] = sum_{j: 0<d<RC, spc(j)=s} exp(-16(d-shf_p)^2)*fc(d)
// B=64, N=256, S=4, P=16, RC=5.2, shf_p = 0.9 + 0.26875*p
// d_in[0]: fp32 [B,256,256]; d_in[1]: int32 [B,256] (1..4); d_out: fp32 [B,256,64]
//
// Block = 256 = 4 waves, 2 rows/wave, grid = B*32 = 2048. __launch_bounds__
// (256,8) forces <=64 VGPR so all 8 blocks/CU are co-resident (single
// generation). dmat loads are nontemporal (L3 is 100% dirty poison after the
// harness's 256MB fill; avoid alloc+evict). seg[]/trip counts pinned to SGPRs
// via readfirstlane.
// Phase A: per-b species permutation (2 ballots, exact bijection).
// Phase B: stage (cA = K*d^2 + log2(fc*mask), cB = -2K*d); invalid -> cA=-inf.
// Phase C: lane=(g,q',s'): term = exp2(fma(cB, shf, cA) + K*shf^2); 8 exps
//          per LDS pair read; quad shfl reduce; coalesced nt stores.

static __device__ __forceinline__ int mbcnt64(uint64_t m) {
    int lo = __builtin_amdgcn_mbcnt_lo((uint32_t)m, 0u);
    return __builtin_amdgcn_mbcnt_hi((uint32_t)(m >> 32), lo);
}

typedef float vfloat2 __attribute__((ext_vector_type(2)));
typedef float vfloat4 __attribute__((ext_vector_type(4)));

#define KNEG (-23.083120654223414f)   /* -16*log2(e) */

__global__ __launch_bounds__(256, 8) void aev_kernel(
    const float* __restrict__ dmat,      // fp32 [B,256,256]
    const int* __restrict__ species,     // int32 [B,256], values 1..4
    float* __restrict__ out)             // fp32 [B,256,64]
{
    __shared__ alignas(16) float2 comp[8][256]; // per-row permuted (cA, cB)
    __shared__ alignas(16) int    pos[256];     // species-major permutation of j
    __shared__ alignas(16) float  red[8][64];   // per-row [s*16+p] results
    __shared__ int cntm[4][4];                  // per-wave per-species counts

    const int tid  = threadIdx.x;
    const int w    = tid >> 6;
    const int lane = tid & 63;
    const int blk  = (int)blockIdx.x;
    const int row0 = blk * 8 + w * 2;    // this wave's rows: row0, row0+1
    const int b    = blk >> 5;

    // ---- issue both global row loads immediately (nontemporal: skip L3) ----
    const vfloat4 qa = __builtin_nontemporal_load(
        (const vfloat4*)(dmat + ((size_t)row0 << 8)) + lane);
    const vfloat4 qb = __builtin_nontemporal_load(
        (const vfloat4*)(dmat + ((size_t)(row0 + 1) << 8)) + lane);

    // ---- phase A: per-b species permutation ----
    int sj = species[(b << 8) + tid] - 1;           // 0..3
    sj = (sj < 0) ? 0 : ((sj > 3) ? 3 : sj);        // insurance
    const uint64_t bs0 = __ballot((sj & 1) != 0);
    const uint64_t bs1 = __ballot((sj & 2) != 0);
    const uint64_t m0 = ~bs0 & ~bs1, m1 = bs0 & ~bs1;
    const uint64_t m2 = ~bs0 &  bs1, m3 = bs0 &  bs1;
    if (lane == 0) {
        cntm[w][0] = __popcll(m0); cntm[w][1] = __popcll(m1);
        cntm[w][2] = __popcll(m2); cntm[w][3] = __popcll(m3);
    }
    uint64_t msel = m0;
    msel = (sj == 1) ? m1 : msel;
    msel = (sj == 2) ? m2 : msel;
    msel = (sj == 3) ? m3 : msel;
    const int rank = mbcnt64(msel);
    __syncthreads();

    // wave-uniform segment bases -> force into SGPRs
    int seg[5];
    seg[0] = 0;
    #pragma unroll
    for (int s = 0; s < 4; ++s)
        seg[s + 1] = __builtin_amdgcn_readfirstlane(
            seg[s] + cntm[0][s] + cntm[1][s] + cntm[2][s] + cntm[3][s]);
    {
        int base = seg[0];
        base = (sj == 1) ? seg[1] : base;
        base = (sj == 2) ? seg[2] : base;
        base = (sj == 3) ? seg[3] : base;
        int wadd = 0;
        #pragma unroll
        for (int w2 = 0; w2 < 3; ++w2) wadd += (w2 < w) ? cntm[w2][sj] : 0;
        pos[tid] = base + wadd + rank;              // exact bijection [0,256)
    }
    __syncthreads();

    // ---- phase B: stage both rows as (cA, cB), permuted ----
    {
        const int4 p4 = *(const int4*)&pos[4 * lane];
        const int   pp[4] = {p4.x, p4.y, p4.z, p4.w};
        const float da[4] = {qa.x, qa.y, qa.z, qa.w};
        const float db[4] = {qb.x, qb.y, qb.z, qb.w};
        const float NINF = -__builtin_inff();
        const int lr = w * 2;
        #pragma unroll
        for (int e = 0; e < 4; ++e) {
            const float dd = da[e];
            const bool  v  = (dd < 5.2f) && (dd != 0.0f);   // false for NaN
            const float x  = v ? dd : 2.6f;                 // cos arg in-domain
            const float fc = 0.5f * __builtin_amdgcn_cosf(x * (0.5f / 5.2f)) + 0.5f;
            const float cA = __builtin_fmaf(KNEG * x, x, __builtin_amdgcn_logf(fc));
            comp[lr][pp[e]] = make_float2(v ? cA : NINF, v ? (-2.0f * KNEG) * x : 0.0f);
        }
        #pragma unroll
        for (int e = 0; e < 4; ++e) {
            const float dd = db[e];
            const bool  v  = (dd < 5.2f) && (dd != 0.0f);
            const float x  = v ? dd : 2.6f;
            const float fc = 0.5f * __builtin_amdgcn_cosf(x * (0.5f / 5.2f)) + 0.5f;
            const float cA = __builtin_fmaf(KNEG * x, x, __builtin_amdgcn_logf(fc));
            comp[lr + 1][pp[e]] = make_float2(v ? cA : NINF, v ? (-2.0f * KNEG) * x : 0.0f);
        }
    }
    __syncthreads();

    // ---- phase C: lane = g*16 + q'*4 + s' ----
    const int g  = lane >> 4;            // 0..3 -> shifts p = 4g..4g+3
    const int qp = (lane >> 2) & 3;      // quad slot within segment
    const int sp = lane & 3;             // owned species segment
    const int lr = w * 2;

    const float shf0 = 0.9f + 0.26875f * (float)(4 * g);   // shf[t] = shf0 + 0.26875*t

    const int sbeg = (sp == 0) ? seg[0] : (sp == 1) ? seg[1] : (sp == 2) ? seg[2] : seg[3];
    const int send = (sp == 0) ? seg[1] : (sp == 1) ? seg[2] : (sp == 2) ? seg[3] : seg[4];
    int maxLen = seg[1] - seg[0];
    maxLen = (seg[2] - seg[1] > maxLen) ? seg[2] - seg[1] : maxLen;
    maxLen = (seg[3] - seg[2] > maxLen) ? seg[3] - seg[2] : maxLen;
    maxLen = (seg[4] - seg[3] > maxLen) ? seg[4] - seg[3] : maxLen;
    const int nIt = __builtin_amdgcn_readfirstlane((maxLen + 3) >> 2);

    const float NINF = -__builtin_inff();
    float a0x = 0.f, a0y = 0.f, a0z = 0.f, a0w = 0.f;   // row0, t=0..3
    float a1x = 0.f, a1y = 0.f, a1z = 0.f, a1w = 0.f;   // row1
    for (int m = 0; m < nIt; ++m) {
        const int k  = sbeg + qp + 4 * m;
        const int kc = (k < 255) ? k : 255;
        const bool live = (k < send);
        const float2 cR0 = comp[lr][kc];
        const float2 cR1 = comp[lr + 1][kc];
        const float A0 = live ? cR0.x : NINF;
        const float A1 = live ? cR1.x : NINF;
        // term = exp2(cB*shf + cA + K*shf^2); dead lanes/tails -> exp2(-inf)=0
        #pragma unroll
        for (int t = 0; t < 4; ++t) {
            const float sh = shf0 + 0.26875f * (float)t;    // rematerialized
            const float kp = KNEG * sh * sh;
            const float e0 = __builtin_amdgcn_exp2f(__builtin_fmaf(cR0.y, sh, A0) + kp);
            const float e1 = __builtin_amdgcn_exp2f(__builtin_fmaf(cR1.y, sh, A1) + kp);
            if (t == 0) { a0x += e0; a1x += e1; }
            if (t == 1) { a0y += e0; a1y += e1; }
            if (t == 2) { a0z += e0; a1z += e1; }
            if (t == 3) { a0w += e0; a1w += e1; }
        }
    }

    // ---- reduce over q' (lanes xor 4, 8) ----
    #pragma unroll
    for (int d = 4; d <= 8; d <<= 1) {
        a0x += __shfl_xor(a0x, d, 64); a0y += __shfl_xor(a0y, d, 64);
        a0z += __shfl_xor(a0z, d, 64); a0w += __shfl_xor(a0w, d, 64);
        a1x += __shfl_xor(a1x, d, 64); a1y += __shfl_xor(a1y, d, 64);
        a1z += __shfl_xor(a1z, d, 64); a1w += __shfl_xor(a1w, d, 64);
    }

    // lanes with q'==0 hold the (g, s') sums: write [s'*16 + 4g .. +3]
    if (qp == 0) {
        float4* r0 = (float4*)&red[lr][(sp << 4) + (g << 2)];
        float4* r1 = (float4*)&red[lr + 1][(sp << 4) + (g << 2)];
        *r0 = make_float4(a0x, a0y, a0z, a0w);
        *r1 = make_float4(a1x, a1y, a1z, a1w);
    }

    // ---- store: wave reads its own rows from red (wave-synchronous) ----
    {
        const int r  = lane >> 5;                   // 0..1 (this wave's rows)
        const int c2 = lane & 31;                   // float2 column
        const float2 rv = ((const float2*)&red[lr + r][0])[c2];
        vfloat2 nv; nv.x = rv.x; nv.y = rv.y;
        vfloat2* dst = (vfloat2*)&out[((size_t)(row0 + r) << 6) + (size_t)(c2 * 2)];
        __builtin_nontemporal_store(nv, dst);
    }
}

extern "C" void kernel_launch(void* const* d_in, const int* in_sizes, int n_in,
                              void* d_out, int out_size, void* d_ws, size_t ws_size,
                              hipStream_t stream) {
    const float* dmat  = (const float*)d_in[0];          // fp32 [B,256,256]
    const int* species = (const int*)d_in[1];            // int32 [B,256]
    float* o           = (float*)d_out;                  // fp32 [B,256,64]
    const int B = in_sizes[1] >> 8;                      // N = 256
    aev_kernel<<<dim3(B * 32), 256, 0, stream>>>(dmat, species, o);
}